// Round 1
// baseline (243.306 us; speedup 1.0000x reference)
//
#include <hip/hip_runtime.h>

typedef __attribute__((ext_vector_type(8))) short short8;
typedef __attribute__((ext_vector_type(4))) float float4_t;
typedef __attribute__((ext_vector_type(16))) float f32x16;
typedef __attribute__((ext_vector_type(4))) unsigned int uint4_t;
typedef __attribute__((ext_vector_type(2))) unsigned int uint2_t;
typedef unsigned short u16;

#define HIDDEN 1024
#define HDIM   64
#define SS     2048
#define TOK    4096
#define QSCALE 0.1803368801111137f   // log2(e) / sqrt(HDIM)

__device__ __forceinline__ unsigned int fbits(float f) {
  unsigned int x; __builtin_memcpy(&x, &f, 4); return x;
}
__device__ __forceinline__ u16 f2bf(float f) {          // round-half-up
  return (u16)((fbits(f) + 0x8000u) >> 16);
}
// two f32 -> packed bf16 pair, round-half-up (3 VALU) / truncate (1 VALU)
__device__ __forceinline__ unsigned int pk2bf(float a, float b) {
  return __builtin_amdgcn_perm(fbits(b) + 0x8000u, fbits(a) + 0x8000u, 0x07060302);
}
__device__ __forceinline__ unsigned int pk2bf_t(float a, float b) {
  return __builtin_amdgcn_perm(fbits(b), fbits(a), 0x07060302);
}

// async global->LDS, 16B/lane; LDS dest must be wave-uniform base + lane*16.
__device__ __forceinline__ void gl_lds16(const u16* g, u16* l) {
  __builtin_amdgcn_global_load_lds(
      (const __attribute__((address_space(1))) unsigned int*)g,
      (__attribute__((address_space(3))) unsigned int*)l, 16, 0, 0);
}

// One launch: convert 4 W (1M elems each) + 3 X (4M each) f32 -> bf16.
// grid (2048, 7): y<4 = W (first 512 x-blocks active), y>=4 = X.
__global__ __launch_bounds__(256) void convert_all(
    const float* __restrict__ w0, const float* __restrict__ w1,
    const float* __restrict__ w2, const float* __restrict__ w3,
    const float* __restrict__ x0, const float* __restrict__ x1,
    const float* __restrict__ x2, u16* __restrict__ Wall, u16* __restrict__ Xall) {
  int y = blockIdx.y;
  const float* src; u16* dst;
  if (y < 4) {
    if (blockIdx.x >= 512) return;
    src = y == 0 ? w0 : y == 1 ? w1 : y == 2 ? w2 : w3;
    dst = Wall + ((size_t)y << 20);
  } else {
    src = y == 4 ? x0 : y == 5 ? x1 : x2;
    dst = Xall + ((size_t)(y - 4) << 22);
  }
  int g = (blockIdx.x * 256 + threadIdx.x) * 8;
  float4_t a = *(const float4_t*)(src + g);
  float4_t b = *(const float4_t*)(src + g + 4);
  uint4_t o;
  o.x = pk2bf(a[0], a[1]); o.y = pk2bf(a[2], a[3]);
  o.z = pk2bf(b[0], b[1]); o.w = pk2bf(b[2], b[3]);
  *(uint4_t*)(dst + g) = o;
}

// C[m][n] = (sum_k X[m][k] * W[n][k] + bias[n]) * oscale.  BK=64, W bf16 via gl_lds.
// Block tile: (MTILES*32) x 128, 4 waves (2x2). LDS rows 64 elems = 8 chunks,
// swizzle pos = c ^ (r&7) (2-way, free). 16 K-iters; 32 MFMA/wave per barrier pair.
// mode 0: Y[m*1024+n] (f32 if OUTF32 else bf16); mode 1 (V transposed, bf16):
//   Y[((m>>11)*1024 + n)*2048 + (m&2047)]
template<int MTILES, bool AXF32, bool OUTF32>
__device__ __forceinline__ void gemm_bt_body(
    const void* __restrict__ X, const u16* __restrict__ Wb,
    const float* __restrict__ bias, void* __restrict__ Y, int mode, float oscale,
    u16* sA, u16* sB, int row0, int col0) {
  const int tid  = threadIdx.x;
  const int wv   = tid >> 6, lane = tid & 63, quad = lane >> 4, ln = lane & 15;
  const int wm   = (wv >> 1) * (MTILES * 16), wn = (wv & 1) * 64;
  constexpr int AITERS = MTILES;        // A chunks = MTILES*32 rows * 8 / 256

  float4_t acc[MTILES][4];
#pragma unroll
  for (int i = 0; i < MTILES; i++)
#pragma unroll
    for (int j = 0; j < 4; j++) acc[i][j] = (float4_t)0.0f;

  for (int kt = 0; kt < 16; ++kt) {
    const int k0 = kt * 64;
    short8 ax[AITERS];
    if (AXF32) {
#pragma unroll
      for (int i = 0; i < AITERS; i++) {
        int idx = i * 256 + tid, r = idx >> 3, c = idx & 7;
        const float* p = (const float*)X + (size_t)(row0 + r) * HIDDEN + k0 + c * 8;
        float4_t a = *(const float4_t*)p;
        float4_t b = *(const float4_t*)(p + 4);
        union { unsigned int u[4]; short8 s; } x;
        x.u[0] = pk2bf(a[0], a[1]); x.u[1] = pk2bf(a[2], a[3]);
        x.u[2] = pk2bf(b[0], b[1]); x.u[3] = pk2bf(b[2], b[3]);
        ax[i] = x.s;
      }
    }
    __syncthreads();                    // prior iteration's LDS reads done
#pragma unroll
    for (int i = 0; i < 4; i++) {       // B: 128 rows x 8 chunks, source-side swizzle
      int idx = i * 256 + tid, r = idx >> 3, c = idx & 7;
      int gc = c ^ (r & 7);
      gl_lds16(Wb + (size_t)(col0 + r) * HIDDEN + k0 + gc * 8, sB + idx * 8);
    }
    if (AXF32) {
#pragma unroll
      for (int i = 0; i < AITERS; i++) { // A: swizzled ds_write of converted regs
        int idx = i * 256 + tid, r = idx >> 3, c = idx & 7;
        int pos = c ^ (r & 7);
        *(short8*)(sA + r * 64 + pos * 8) = ax[i];
      }
    } else {
#pragma unroll
      for (int i = 0; i < AITERS; i++) { // A: gl_lds from bf16, source-side swizzle
        int idx = i * 256 + tid, r = idx >> 3, c = idx & 7;
        int gc = c ^ (r & 7);
        gl_lds16((const u16*)X + (size_t)(row0 + r) * HIDDEN + k0 + gc * 8, sA + idx * 8);
      }
    }
    __syncthreads();                    // drains vmcnt (gl_lds) + lgkmcnt

    short8 af[MTILES][2], bfr[4][2];
#pragma unroll
    for (int mt = 0; mt < MTILES; mt++)
#pragma unroll
      for (int kk = 0; kk < 2; kk++) {
        int r = wm + mt * 16 + ln;
        int ch = kk * 4 + quad;
        af[mt][kk] = *(const short8*)(sA + r * 64 + (ch ^ (r & 7)) * 8);
      }
#pragma unroll
    for (int nt = 0; nt < 4; nt++)
#pragma unroll
      for (int kk = 0; kk < 2; kk++) {
        int r = wn + nt * 16 + ln;
        int ch = kk * 4 + quad;
        bfr[nt][kk] = *(const short8*)(sB + r * 64 + (ch ^ (r & 7)) * 8);
      }
#pragma unroll
    for (int kk = 0; kk < 2; kk++)
#pragma unroll
      for (int mt = 0; mt < MTILES; mt++)
#pragma unroll
        for (int nt = 0; nt < 4; nt++)
          acc[mt][nt] = __builtin_amdgcn_mfma_f32_16x16x32_bf16(af[mt][kk], bfr[nt][kk], acc[mt][nt], 0, 0, 0);
  }

  float bcol[4];
#pragma unroll
  for (int nt = 0; nt < 4; nt++) bcol[nt] = bias[col0 + wn + nt * 16 + ln];
#pragma unroll
  for (int mt = 0; mt < MTILES; mt++)
#pragma unroll
    for (int nt = 0; nt < 4; nt++) {
      int n = col0 + wn + nt * 16 + ln;
#pragma unroll
      for (int r = 0; r < 4; r++) {
        int m = row0 + wm + mt * 16 + quad * 4 + r;
        float v = (acc[mt][nt][r] + bcol[nt]) * oscale;
        if (mode == 0) {
          if (OUTF32) ((float*)Y)[(size_t)m * HIDDEN + n] = v;
          else        ((u16*)Y)[(size_t)m * HIDDEN + n] = f2bf(v);
        } else {
          ((u16*)Y)[((size_t)(m >> 11) * HIDDEN + n) * SS + (m & 2047)] = f2bf(v);
        }
      }
    }
}

// all-bf16 QKV (X pre-converted into Xall)
__global__ __launch_bounds__(256) void qkv_gemm_bf16(
    const u16* __restrict__ Xall, const u16* __restrict__ Wall,
    const float* __restrict__ bq, const float* __restrict__ bk, const float* __restrict__ bv,
    u16* __restrict__ Qp, u16* __restrict__ Kp, u16* __restrict__ Vt) {
  __shared__ u16 sA[128 * 64];
  __shared__ u16 sB[128 * 64];
  int z = blockIdx.z;
  const u16* X = Xall + ((size_t)z << 22);
  const u16* W = Wall + ((size_t)z << 20);
  const float* Bp = z == 0 ? bq : z == 1 ? bk : bv;
  u16* Y = z == 0 ? Qp : z == 1 ? Kp : Vt;
  int mode = (z == 2) ? 1 : 0;
  float sc = (z == 0) ? QSCALE : 1.0f;
  gemm_bt_body<4, false, false>(X, W, Bp, Y, mode, sc, sA, sB, blockIdx.y * 128, blockIdx.x * 128);
}

// fallback: X staged from f32 in-kernel (workspace too small for Xall)
__global__ __launch_bounds__(256) void qkv_gemm_f32(
    const float* __restrict__ xq, const float* __restrict__ xk, const float* __restrict__ xv,
    const u16* __restrict__ Wall,
    const float* __restrict__ bq, const float* __restrict__ bk, const float* __restrict__ bv,
    u16* __restrict__ Qp, u16* __restrict__ Kp, u16* __restrict__ Vt) {
  __shared__ u16 sA[128 * 64];
  __shared__ u16 sB[128 * 64];
  int z = blockIdx.z;
  const float* X = z == 0 ? xq : z == 1 ? xk : xv;
  const u16* W = Wall + ((size_t)z << 20);
  const float* Bp = z == 0 ? bq : z == 1 ? bk : bv;
  u16* Y = z == 0 ? Qp : z == 1 ? Kp : Vt;
  int mode = (z == 2) ? 1 : 0;
  float sc = (z == 0) ? QSCALE : 1.0f;
  gemm_bt_body<4, true, false>(X, W, Bp, Y, mode, sc, sA, sB, blockIdx.y * 128, blockIdx.x * 128);
}

// 64-row tiles -> 512 blocks (2/CU); BK=64, 24 KB LDS
__global__ __launch_bounds__(256) void out_gemm(
    const u16* __restrict__ X, const u16* __restrict__ Wob,
    const float* __restrict__ bias, float* __restrict__ Y) {
  __shared__ u16 sA[64 * 64];
  __shared__ u16 sB[128 * 64];
  gemm_bt_body<2, false, true>(X, Wob, bias, Y, 0, 1.0f, sA, sB, blockIdx.y * 64, blockIdx.x * 128);
}

// Flash attention v2: 32x32x16 MFMA, 64 q-rows/wave, 256 q-rows/block,
// double-buffered K/V prefetch (1 barrier per tile), in-register P via
// cvt_pk + permlane32_swap, VALU denominator, XCD-grouped block decode.
// Grid: 256 blocks (1/CU). bid = qt<<5 | (h<<1 | b)  -> 8 blocks sharing one
// (h,b)'s K/V (512 KB) land on the same XCD (bid%8 const) => L2-resident KV.
__global__ __launch_bounds__(256, 1) void attn(
    const u16* __restrict__ Qp, const u16* __restrict__ Kp,
    const u16* __restrict__ Vt, u16* __restrict__ Ctx) {
  __shared__ u16 sK[2][128 * 64];   // [key][d],   8 chunks/row, pos = c ^ (r&7)
  __shared__ u16 sV[2][64 * 128];   // [d][key],  16 chunks/row, pos = c ^ (r&15)
  const int tid  = threadIdx.x;
  const int wv   = tid >> 6, lane = tid & 63;
  const int l5   = lane >> 5, ln = lane & 31;
  const int f = blockIdx.x;
  const int qt = f >> 5, g = f & 31, h = g >> 1, b = g & 1;
  const int row0w = qt * 256 + wv * 64;

  // Q fragments (B-operand): lane -> n = qrow = ln, k(d) = kk*16 + l5*8 + j
  short8 qf[2][4];
#pragma unroll
  for (int qg = 0; qg < 2; ++qg)
#pragma unroll
    for (int kk = 0; kk < 4; ++kk)
      qf[qg][kk] = *(const short8*)(Qp + (size_t)(b * SS + row0w + qg * 32 + ln) * HIDDEN
                                    + h * HDIM + kk * 16 + l5 * 8);

  f32x16 oacc[2][2];                 // [qg][dg]: O^T, d = dg*32+(reg&3)+8*(reg>>2)+4*l5
#pragma unroll
  for (int qg = 0; qg < 2; ++qg)
#pragma unroll
    for (int dg = 0; dg < 2; ++dg) oacc[qg][dg] = (f32x16)0.0f;
  float dsum[2] = {0.f, 0.f};

  auto stage = [&](int buf, int kt) {
#pragma unroll
    for (int p = 0; p < 4; ++p) {
      int off = p * 256 + tid;
      { int r = off >> 3, c = off & 7;  int gc = c ^ (r & 7);
        gl_lds16(Kp + (size_t)(b * SS + kt * 128 + r) * HIDDEN + h * HDIM + gc * 8,
                 &sK[buf][0] + off * 8); }
      { int r = off >> 4, c = off & 15; int gc = c ^ (r & 15);
        gl_lds16(Vt + ((size_t)b * HIDDEN + h * HDIM + r) * SS + kt * 128 + gc * 8,
                 &sV[buf][0] + off * 8); }
    }
  };

  stage(0, 0);
  __syncthreads();                       // drains prologue vmcnt

  for (int kt = 0; kt < 16; ++kt) {
    const int cur = kt & 1;
    if (kt < 15) stage(cur ^ 1, kt + 1); // prefetch next tile; lands during compute
    const u16* K_ = &sK[cur][0];
    const u16* V_ = &sV[cur][0];

#pragma unroll
    for (int kgg = 0; kgg < 4; ++kgg) {  // 4 key-groups of 32 per tile
      // S^T = K . Q^T  (A = K-tile rows, B = Q)
      f32x16 st[2];
      st[0] = (f32x16)0.0f; st[1] = (f32x16)0.0f;
#pragma unroll
      for (int kk = 0; kk < 4; ++kk) {
        int r = kgg * 32 + ln;
        int ch = kk * 2 + l5;
        short8 kf = *(const short8*)(K_ + r * 64 + ((ch ^ (r & 7))) * 8);
        st[0] = __builtin_amdgcn_mfma_f32_32x32x16_bf16(kf, qf[0][kk], st[0], 0, 0, 0);
        st[1] = __builtin_amdgcn_mfma_f32_32x32x16_bf16(kf, qf[1][kk], st[1], 0, 0, 0);
      }

      // P = exp2(S); denominator add-tree; pack -> PV B-frags via permlane32_swap.
      // st value at (key = kgg*32 + (reg&3)+8*(reg>>2)+4*l5, qrow = ln).
      union PF { unsigned int u[4]; short8 s; };
      PF pfr[2][2];                      // [qg][ks]: keys kgg*32 + ks*16 + (0..15)
#pragma unroll
      for (int qg = 0; qg < 2; ++qg) {
        float p[16];
#pragma unroll
        for (int r = 0; r < 16; ++r)
          p[r] = __builtin_amdgcn_exp2f(fminf(st[qg][r], 80.f));
        dsum[qg] += (((p[0] + p[1]) + (p[2] + p[3])) + ((p[4] + p[5]) + (p[6] + p[7])))
                  + (((p[8] + p[9]) + (p[10] + p[11])) + ((p[12] + p[13]) + (p[14] + p[15])));
        unsigned int pk[8];
#pragma unroll
        for (int i = 0; i < 8; ++i) pk[i] = pk2bf_t(p[2 * i], p[2 * i + 1]);
        // swap vdst.hi <-> vsrc.lo: res.x = {lo:a_lo, hi:b_lo}, res.y = {lo:a_hi, hi:b_hi}
        uint2_t r02 = __builtin_amdgcn_permlane32_swap(pk[0], pk[2], false, false);
        uint2_t r13 = __builtin_amdgcn_permlane32_swap(pk[1], pk[3], false, false);
        uint2_t r46 = __builtin_amdgcn_permlane32_swap(pk[4], pk[6], false, false);
        uint2_t r57 = __builtin_amdgcn_permlane32_swap(pk[5], pk[7], false, false);
        pfr[qg][0].u[0] = r02.x; pfr[qg][0].u[1] = r13.x;
        pfr[qg][0].u[2] = r02.y; pfr[qg][0].u[3] = r13.y;
        pfr[qg][1].u[0] = r46.x; pfr[qg][1].u[1] = r57.x;
        pfr[qg][1].u[2] = r46.y; pfr[qg][1].u[3] = r57.y;
      }

      // O^T += V^T . P^T
#pragma unroll
      for (int ks = 0; ks < 2; ++ks) {
        int ch = (kgg * 2 + ks) * 2 + l5;          // key chunk of 8 within tile
#pragma unroll
        for (int dg = 0; dg < 2; ++dg) {
          int r = dg * 32 + ln;
          short8 vf = *(const short8*)(V_ + r * 128 + ((ch ^ (r & 15))) * 8);
          oacc[0][dg] = __builtin_amdgcn_mfma_f32_32x32x16_bf16(vf, pfr[0][ks].s, oacc[0][dg], 0, 0, 0);
          oacc[1][dg] = __builtin_amdgcn_mfma_f32_32x32x16_bf16(vf, pfr[1][ks].s, oacc[1][dg], 0, 0, 0);
        }
      }
    }
    __syncthreads();   // drains prefetch vmcnt; all waves done reading cur buffer
  }

  // denominator: lane halves hold complementary keys -> one xor-32 shuffle
  float inv[2];
#pragma unroll
  for (int qg = 0; qg < 2; ++qg) {
    float s = dsum[qg] + __shfl_xor(dsum[qg], 32, 64);
    inv[qg] = 1.0f / s;
  }

  // epilogue: scale, transpose via wave-private LDS (reuse sK), coalesced store
  u16* ep = ((u16*)sK) + wv * 4096;     // 64 rows x 64 d per wave
#pragma unroll
  for (int qg = 0; qg < 2; ++qg) {
    int row = qg * 32 + ln;
#pragma unroll
    for (int dg = 0; dg < 2; ++dg)
#pragma unroll
      for (int i = 0; i < 4; ++i) {     // regs 4i..4i+3 = d dg*32+8i+4*l5 .. +3
        uint2_t w;
        w.x = pk2bf(oacc[qg][dg][4 * i] * inv[qg],     oacc[qg][dg][4 * i + 1] * inv[qg]);
        w.y = pk2bf(oacc[qg][dg][4 * i + 2] * inv[qg], oacc[qg][dg][4 * i + 3] * inv[qg]);
        int c = dg * 4 + i;
        *(uint2_t*)(ep + row * 64 + ((c ^ (row & 7))) * 8 + l5 * 4) = w;
      }
  }
  // wave-private: lgkmcnt orders ds_write -> ds_read, no barrier needed
#pragma unroll
  for (int ps = 0; ps < 8; ++ps) {
    int r = ps * 8 + (lane >> 3);
    int c = lane & 7;
    short8 o8 = *(const short8*)(ep + r * 64 + ((c ^ (r & 7))) * 8);
    *(short8*)(Ctx + (size_t)(b * SS + row0w + r) * HIDDEN + h * HDIM + c * 8) = o8;
  }
}

extern "C" void kernel_launch(void* const* d_in, const int* in_sizes, int n_in,
                              void* d_out, int out_size, void* d_ws, size_t ws_size,
                              hipStream_t stream) {
  const float* q  = (const float*)d_in[0];
  const float* k  = (const float*)d_in[1];
  const float* v  = (const float*)d_in[2];
  const float* Wq = (const float*)d_in[3];
  const float* bq = (const float*)d_in[4];
  const float* Wk = (const float*)d_in[5];
  const float* bk = (const float*)d_in[6];
  const float* Wv = (const float*)d_in[7];
  const float* bv = (const float*)d_in[8];
  const float* Wo = (const float*)d_in[9];
  const float* bo = (const float*)d_in[10];

  u16* Qp   = (u16*)d_ws;                     //  8 MB
  u16* Kp   = Qp + (size_t)TOK * HIDDEN;      //  8 MB
  u16* Vt   = Kp + (size_t)TOK * HIDDEN;      //  8 MB
  u16* Wall = Vt + (size_t)TOK * HIDDEN;      //  8 MB (Wq,Wk,Wv,Wo bf16)
  u16* Xall = Wall + (4u << 20);              // 24 MB (q,k,v bf16)
  u16* Cx   = Qp;   // attention writes ctx in-place over Q (block-disjoint regions)
  bool useX = ws_size >= (size_t)56 * 1024 * 1024;

  dim3 blk(256);
  if (useX) {
    hipLaunchKernelGGL(convert_all, dim3(2048, 7), blk, 0, stream,
                       Wq, Wk, Wv, Wo, q, k, v, Wall, Xall);
    hipLaunchKernelGGL(qkv_gemm_bf16, dim3(8, 32, 3), blk, 0, stream,
                       Xall, Wall, bq, bk, bv, Qp, Kp, Vt);
  } else {
    hipLaunchKernelGGL(convert_all, dim3(512, 4), blk, 0, stream,
                       Wq, Wk, Wv, Wo, q, k, v, Wall, Wall);
    hipLaunchKernelGGL(qkv_gemm_f32, dim3(8, 32, 3), blk, 0, stream,
                       q, k, v, Wall, bq, bk, bv, Qp, Kp, Vt);
  }
  hipLaunchKernelGGL(attn, dim3(256), blk, 0, stream, Qp, Kp, Vt, Cx);
  hipLaunchKernelGGL(out_gemm, dim3(8, 64, 1), blk, 0, stream,
                     Cx, Wall + (3u << 20), bo, (float*)d_out);
}

// Round 2
// 213.780 us; speedup vs baseline: 1.1381x; 1.1381x over previous
//
#include <hip/hip_runtime.h>

typedef __attribute__((ext_vector_type(8))) short short8;
typedef __attribute__((ext_vector_type(4))) float float4_t;
typedef __attribute__((ext_vector_type(16))) float f32x16;
typedef __attribute__((ext_vector_type(4))) unsigned int uint4_t;
typedef __attribute__((ext_vector_type(2))) unsigned int uint2_t;
typedef unsigned short u16;

#define HIDDEN 1024
#define HDIM   64
#define SS     2048
#define TOK    4096
#define QSCALE 0.1803368801111137f   // log2(e) / sqrt(HDIM)

__device__ __forceinline__ unsigned int fbits(float f) {
  unsigned int x; __builtin_memcpy(&x, &f, 4); return x;
}
__device__ __forceinline__ u16 f2bf(float f) {          // round-half-up
  return (u16)((fbits(f) + 0x8000u) >> 16);
}
// two f32 -> packed bf16 pair, round-half-up (3 VALU) / truncate (1 VALU)
__device__ __forceinline__ unsigned int pk2bf(float a, float b) {
  return __builtin_amdgcn_perm(fbits(b) + 0x8000u, fbits(a) + 0x8000u, 0x07060302);
}
__device__ __forceinline__ unsigned int pk2bf_t(float a, float b) {
  return __builtin_amdgcn_perm(fbits(b), fbits(a), 0x07060302);
}

// async global->LDS, 16B/lane; LDS dest must be wave-uniform base + lane*16.
__device__ __forceinline__ void gl_lds16(const u16* g, u16* l) {
  __builtin_amdgcn_global_load_lds(
      (const __attribute__((address_space(1))) unsigned int*)g,
      (__attribute__((address_space(3))) unsigned int*)l, 16, 0, 0);
}

// One launch: convert 4 W (1M elems each) + 3 X (4M each) f32 -> bf16.
// grid (2048, 7): y<4 = W (first 512 x-blocks active), y>=4 = X.
__global__ __launch_bounds__(256) void convert_all(
    const float* __restrict__ w0, const float* __restrict__ w1,
    const float* __restrict__ w2, const float* __restrict__ w3,
    const float* __restrict__ x0, const float* __restrict__ x1,
    const float* __restrict__ x2, u16* __restrict__ Wall, u16* __restrict__ Xall) {
  int y = blockIdx.y;
  const float* src; u16* dst;
  if (y < 4) {
    if (blockIdx.x >= 512) return;
    src = y == 0 ? w0 : y == 1 ? w1 : y == 2 ? w2 : w3;
    dst = Wall + ((size_t)y << 20);
  } else {
    src = y == 4 ? x0 : y == 5 ? x1 : x2;
    dst = Xall + ((size_t)(y - 4) << 22);
  }
  int g = (blockIdx.x * 256 + threadIdx.x) * 8;
  float4_t a = *(const float4_t*)(src + g);
  float4_t b = *(const float4_t*)(src + g + 4);
  uint4_t o;
  o.x = pk2bf(a[0], a[1]); o.y = pk2bf(a[2], a[3]);
  o.z = pk2bf(b[0], b[1]); o.w = pk2bf(b[2], b[3]);
  *(uint4_t*)(dst + g) = o;
}

// C[m][n] = (sum_k X[m][k] * W[n][k] + bias[n]) * oscale.  BK=64, W bf16 via gl_lds.
// Block tile: (MTILES*32) x 128, 4 waves (2x2). LDS rows 64 elems = 8 chunks,
// swizzle pos = c ^ (r&7) (2-way, free). 16 K-iters; 32 MFMA/wave per barrier pair.
// mode 0: Y[m*1024+n] (f32 if OUTF32 else bf16); mode 1 (V transposed, bf16):
//   Y[((m>>11)*1024 + n)*2048 + (m&2047)]
template<int MTILES, bool AXF32, bool OUTF32>
__device__ __forceinline__ void gemm_bt_body(
    const void* __restrict__ X, const u16* __restrict__ Wb,
    const float* __restrict__ bias, void* __restrict__ Y, int mode, float oscale,
    u16* sA, u16* sB, int row0, int col0) {
  const int tid  = threadIdx.x;
  const int wv   = tid >> 6, lane = tid & 63, quad = lane >> 4, ln = lane & 15;
  const int wm   = (wv >> 1) * (MTILES * 16), wn = (wv & 1) * 64;
  constexpr int AITERS = MTILES;        // A chunks = MTILES*32 rows * 8 / 256

  float4_t acc[MTILES][4];
#pragma unroll
  for (int i = 0; i < MTILES; i++)
#pragma unroll
    for (int j = 0; j < 4; j++) acc[i][j] = (float4_t)0.0f;

  for (int kt = 0; kt < 16; ++kt) {
    const int k0 = kt * 64;
    short8 ax[AITERS];
    if (AXF32) {
#pragma unroll
      for (int i = 0; i < AITERS; i++) {
        int idx = i * 256 + tid, r = idx >> 3, c = idx & 7;
        const float* p = (const float*)X + (size_t)(row0 + r) * HIDDEN + k0 + c * 8;
        float4_t a = *(const float4_t*)p;
        float4_t b = *(const float4_t*)(p + 4);
        union { unsigned int u[4]; short8 s; } x;
        x.u[0] = pk2bf(a[0], a[1]); x.u[1] = pk2bf(a[2], a[3]);
        x.u[2] = pk2bf(b[0], b[1]); x.u[3] = pk2bf(b[2], b[3]);
        ax[i] = x.s;
      }
    }
    __syncthreads();                    // prior iteration's LDS reads done
#pragma unroll
    for (int i = 0; i < 4; i++) {       // B: 128 rows x 8 chunks, source-side swizzle
      int idx = i * 256 + tid, r = idx >> 3, c = idx & 7;
      int gc = c ^ (r & 7);
      gl_lds16(Wb + (size_t)(col0 + r) * HIDDEN + k0 + gc * 8, sB + idx * 8);
    }
    if (AXF32) {
#pragma unroll
      for (int i = 0; i < AITERS; i++) { // A: swizzled ds_write of converted regs
        int idx = i * 256 + tid, r = idx >> 3, c = idx & 7;
        int pos = c ^ (r & 7);
        *(short8*)(sA + r * 64 + pos * 8) = ax[i];
      }
    } else {
#pragma unroll
      for (int i = 0; i < AITERS; i++) { // A: gl_lds from bf16, source-side swizzle
        int idx = i * 256 + tid, r = idx >> 3, c = idx & 7;
        int gc = c ^ (r & 7);
        gl_lds16((const u16*)X + (size_t)(row0 + r) * HIDDEN + k0 + gc * 8, sA + idx * 8);
      }
    }
    __syncthreads();                    // drains vmcnt (gl_lds) + lgkmcnt

    short8 af[MTILES][2], bfr[4][2];
#pragma unroll
    for (int mt = 0; mt < MTILES; mt++)
#pragma unroll
      for (int kk = 0; kk < 2; kk++) {
        int r = wm + mt * 16 + ln;
        int ch = kk * 4 + quad;
        af[mt][kk] = *(const short8*)(sA + r * 64 + (ch ^ (r & 7)) * 8);
      }
#pragma unroll
    for (int nt = 0; nt < 4; nt++)
#pragma unroll
      for (int kk = 0; kk < 2; kk++) {
        int r = wn + nt * 16 + ln;
        int ch = kk * 4 + quad;
        bfr[nt][kk] = *(const short8*)(sB + r * 64 + (ch ^ (r & 7)) * 8);
      }
#pragma unroll
    for (int kk = 0; kk < 2; kk++)
#pragma unroll
      for (int mt = 0; mt < MTILES; mt++)
#pragma unroll
        for (int nt = 0; nt < 4; nt++)
          acc[mt][nt] = __builtin_amdgcn_mfma_f32_16x16x32_bf16(af[mt][kk], bfr[nt][kk], acc[mt][nt], 0, 0, 0);
  }

  float bcol[4];
#pragma unroll
  for (int nt = 0; nt < 4; nt++) bcol[nt] = bias[col0 + wn + nt * 16 + ln];
#pragma unroll
  for (int mt = 0; mt < MTILES; mt++)
#pragma unroll
    for (int nt = 0; nt < 4; nt++) {
      int n = col0 + wn + nt * 16 + ln;
#pragma unroll
      for (int r = 0; r < 4; r++) {
        int m = row0 + wm + mt * 16 + quad * 4 + r;
        float v = (acc[mt][nt][r] + bcol[nt]) * oscale;
        if (mode == 0) {
          if (OUTF32) ((float*)Y)[(size_t)m * HIDDEN + n] = v;
          else        ((u16*)Y)[(size_t)m * HIDDEN + n] = f2bf(v);
        } else {
          ((u16*)Y)[((size_t)(m >> 11) * HIDDEN + n) * SS + (m & 2047)] = f2bf(v);
        }
      }
    }
}

// all-bf16 QKV (X pre-converted into Xall)
__global__ __launch_bounds__(256) void qkv_gemm_bf16(
    const u16* __restrict__ Xall, const u16* __restrict__ Wall,
    const float* __restrict__ bq, const float* __restrict__ bk, const float* __restrict__ bv,
    u16* __restrict__ Qp, u16* __restrict__ Kp, u16* __restrict__ Vt) {
  __shared__ u16 sA[128 * 64];
  __shared__ u16 sB[128 * 64];
  int z = blockIdx.z;
  const u16* X = Xall + ((size_t)z << 22);
  const u16* W = Wall + ((size_t)z << 20);
  const float* Bp = z == 0 ? bq : z == 1 ? bk : bv;
  u16* Y = z == 0 ? Qp : z == 1 ? Kp : Vt;
  int mode = (z == 2) ? 1 : 0;
  float sc = (z == 0) ? QSCALE : 1.0f;
  gemm_bt_body<4, false, false>(X, W, Bp, Y, mode, sc, sA, sB, blockIdx.y * 128, blockIdx.x * 128);
}

// fallback: X staged from f32 in-kernel (workspace too small for Xall)
__global__ __launch_bounds__(256) void qkv_gemm_f32(
    const float* __restrict__ xq, const float* __restrict__ xk, const float* __restrict__ xv,
    const u16* __restrict__ Wall,
    const float* __restrict__ bq, const float* __restrict__ bk, const float* __restrict__ bv,
    u16* __restrict__ Qp, u16* __restrict__ Kp, u16* __restrict__ Vt) {
  __shared__ u16 sA[128 * 64];
  __shared__ u16 sB[128 * 64];
  int z = blockIdx.z;
  const float* X = z == 0 ? xq : z == 1 ? xk : xv;
  const u16* W = Wall + ((size_t)z << 20);
  const float* Bp = z == 0 ? bq : z == 1 ? bk : bv;
  u16* Y = z == 0 ? Qp : z == 1 ? Kp : Vt;
  int mode = (z == 2) ? 1 : 0;
  float sc = (z == 0) ? QSCALE : 1.0f;
  gemm_bt_body<4, true, false>(X, W, Bp, Y, mode, sc, sA, sB, blockIdx.y * 128, blockIdx.x * 128);
}

// 64-row tiles -> 512 blocks (2/CU); BK=64, 24 KB LDS
__global__ __launch_bounds__(256) void out_gemm(
    const u16* __restrict__ X, const u16* __restrict__ Wob,
    const float* __restrict__ bias, float* __restrict__ Y) {
  __shared__ u16 sA[64 * 64];
  __shared__ u16 sB[128 * 64];
  gemm_bt_body<2, false, true>(X, Wob, bias, Y, 0, 1.0f, sA, sB, blockIdx.y * 64, blockIdx.x * 128);
}

// Flash attention v3: 32x32x16 MFMA, 32 q-rows/wave (2048 waves = 2/SIMD),
// 128 q-rows/block, 512 blocks (2/CU), double-buffered K/V prefetch,
// in-register P via cvt_pk + permlane32_swap, VALU denominator.
// bid = qt<<5 | (h<<1 | b): blocks sharing one (h,b)'s K/V have bid%8 const
// -> same XCD -> KV (512 KB x 4 sets = 2 MB) stays L2-resident.
__global__ __launch_bounds__(256, 2) void attn(
    const u16* __restrict__ Qp, const u16* __restrict__ Kp,
    const u16* __restrict__ Vt, u16* __restrict__ Ctx) {
  __shared__ u16 sK[2][128 * 64];   // [key][d],   8 chunks/row, pos = c ^ (r&7)
  __shared__ u16 sV[2][64 * 128];   // [d][key],  16 chunks/row, pos = c ^ (r&15)
  const int tid  = threadIdx.x;
  const int wv   = tid >> 6, lane = tid & 63;
  const int l5   = lane >> 5, ln = lane & 31;
  const int f = blockIdx.x;
  const int qt = f >> 5, g = f & 31, h = g >> 1, b = g & 1;
  const int row0w = qt * 128 + wv * 32;

  // Q fragments (B-operand): lane -> n = qrow = ln, k(d) = kk*16 + l5*8 + j
  short8 qf[4];
#pragma unroll
  for (int kk = 0; kk < 4; ++kk)
    qf[kk] = *(const short8*)(Qp + (size_t)(b * SS + row0w + ln) * HIDDEN
                              + h * HDIM + kk * 16 + l5 * 8);

  f32x16 oacc[2];                    // [dg]: O^T, d = dg*32+(reg&3)+8*(reg>>2)+4*l5
  oacc[0] = (f32x16)0.0f; oacc[1] = (f32x16)0.0f;
  float dsum = 0.f;

  auto stage = [&](int buf, int kt) {
#pragma unroll
    for (int p = 0; p < 4; ++p) {
      int off = p * 256 + tid;
      { int r = off >> 3, c = off & 7;  int gc = c ^ (r & 7);
        gl_lds16(Kp + (size_t)(b * SS + kt * 128 + r) * HIDDEN + h * HDIM + gc * 8,
                 &sK[buf][0] + off * 8); }
      { int r = off >> 4, c = off & 15; int gc = c ^ (r & 15);
        gl_lds16(Vt + ((size_t)b * HIDDEN + h * HDIM + r) * SS + kt * 128 + gc * 8,
                 &sV[buf][0] + off * 8); }
    }
  };

  stage(0, 0);
  __syncthreads();                       // drains prologue vmcnt

  for (int kt = 0; kt < 16; ++kt) {
    const int cur = kt & 1;
    if (kt < 15) stage(cur ^ 1, kt + 1); // prefetch next tile; lands during compute
    const u16* K_ = &sK[cur][0];
    const u16* V_ = &sV[cur][0];

#pragma unroll
    for (int kgg = 0; kgg < 4; ++kgg) {  // 4 key-groups of 32 per tile
      // S^T = K . Q^T  (A = K-tile rows, B = Q)
      f32x16 st = (f32x16)0.0f;
#pragma unroll
      for (int kk = 0; kk < 4; ++kk) {
        int r = kgg * 32 + ln;
        int ch = kk * 2 + l5;
        short8 kf = *(const short8*)(K_ + r * 64 + ((ch ^ (r & 7))) * 8);
        st = __builtin_amdgcn_mfma_f32_32x32x16_bf16(kf, qf[kk], st, 0, 0, 0);
      }

      // P = exp2(S); denominator add-tree; pack -> PV B-frags via permlane32_swap.
      // st value at (key = kgg*32 + (reg&3)+8*(reg>>2)+4*l5, qrow = ln).
      union PF { unsigned int u[4]; short8 s; };
      PF pfr[2];                         // [ks]: keys kgg*32 + ks*16 + (0..15)
      {
        float p[16];
#pragma unroll
        for (int r = 0; r < 16; ++r)
          p[r] = __builtin_amdgcn_exp2f(fminf(st[r], 80.f));
        dsum += (((p[0] + p[1]) + (p[2] + p[3])) + ((p[4] + p[5]) + (p[6] + p[7])))
              + (((p[8] + p[9]) + (p[10] + p[11])) + ((p[12] + p[13]) + (p[14] + p[15])));
        unsigned int pk[8];
#pragma unroll
        for (int i = 0; i < 8; ++i) pk[i] = pk2bf_t(p[2 * i], p[2 * i + 1]);
        // swap vdst.hi <-> vsrc.lo: res.x = {lo:a_lo, hi:b_lo}, res.y = {lo:a_hi, hi:b_hi}
        uint2_t r02 = __builtin_amdgcn_permlane32_swap(pk[0], pk[2], false, false);
        uint2_t r13 = __builtin_amdgcn_permlane32_swap(pk[1], pk[3], false, false);
        uint2_t r46 = __builtin_amdgcn_permlane32_swap(pk[4], pk[6], false, false);
        uint2_t r57 = __builtin_amdgcn_permlane32_swap(pk[5], pk[7], false, false);
        pfr[0].u[0] = r02.x; pfr[0].u[1] = r13.x;
        pfr[0].u[2] = r02.y; pfr[0].u[3] = r13.y;
        pfr[1].u[0] = r46.x; pfr[1].u[1] = r57.x;
        pfr[1].u[2] = r46.y; pfr[1].u[3] = r57.y;
      }

      // O^T += V^T . P^T
#pragma unroll
      for (int ks = 0; ks < 2; ++ks) {
        int ch = (kgg * 2 + ks) * 2 + l5;          // key chunk of 8 within tile
#pragma unroll
        for (int dg = 0; dg < 2; ++dg) {
          int r = dg * 32 + ln;
          short8 vf = *(const short8*)(V_ + r * 128 + ((ch ^ (r & 15))) * 8);
          oacc[dg] = __builtin_amdgcn_mfma_f32_32x32x16_bf16(vf, pfr[ks].s, oacc[dg], 0, 0, 0);
        }
      }
    }
    __syncthreads();   // drains prefetch vmcnt; all waves done reading cur buffer
  }

  // denominator: lane halves hold complementary keys -> one xor-32 shuffle
  float s = dsum + __shfl_xor(dsum, 32, 64);
  float inv = 1.0f / s;

  // epilogue: scale, transpose via wave-private LDS (reuse sK), coalesced store
  u16* ep = ((u16*)sK) + wv * 2048;     // 32 rows x 64 d per wave
  {
    int row = ln;
#pragma unroll
    for (int dg = 0; dg < 2; ++dg)
#pragma unroll
      for (int i = 0; i < 4; ++i) {     // regs 4i..4i+3 = d dg*32+8i+4*l5 .. +3
        uint2_t w;
        w.x = pk2bf(oacc[dg][4 * i] * inv,     oacc[dg][4 * i + 1] * inv);
        w.y = pk2bf(oacc[dg][4 * i + 2] * inv, oacc[dg][4 * i + 3] * inv);
        int c = dg * 4 + i;
        *(uint2_t*)(ep + row * 64 + ((c ^ (row & 7))) * 8 + l5 * 4) = w;
      }
  }
  // wave-private: lgkmcnt orders ds_write -> ds_read, no barrier needed
#pragma unroll
  for (int ps = 0; ps < 4; ++ps) {
    int r = ps * 8 + (lane >> 3);
    int c = lane & 7;
    short8 o8 = *(const short8*)(ep + r * 64 + ((c ^ (r & 7))) * 8);
    *(short8*)(Ctx + (size_t)(b * SS + row0w + r) * HIDDEN + h * HDIM + c * 8) = o8;
  }
}

extern "C" void kernel_launch(void* const* d_in, const int* in_sizes, int n_in,
                              void* d_out, int out_size, void* d_ws, size_t ws_size,
                              hipStream_t stream) {
  const float* q  = (const float*)d_in[0];
  const float* k  = (const float*)d_in[1];
  const float* v  = (const float*)d_in[2];
  const float* Wq = (const float*)d_in[3];
  const float* bq = (const float*)d_in[4];
  const float* Wk = (const float*)d_in[5];
  const float* bk = (const float*)d_in[6];
  const float* Wv = (const float*)d_in[7];
  const float* bv = (const float*)d_in[8];
  const float* Wo = (const float*)d_in[9];
  const float* bo = (const float*)d_in[10];

  u16* Qp   = (u16*)d_ws;                     //  8 MB
  u16* Kp   = Qp + (size_t)TOK * HIDDEN;      //  8 MB
  u16* Vt   = Kp + (size_t)TOK * HIDDEN;      //  8 MB
  u16* Wall = Vt + (size_t)TOK * HIDDEN;      //  8 MB (Wq,Wk,Wv,Wo bf16)
  u16* Xall = Wall + (4u << 20);              // 24 MB (q,k,v bf16)
  u16* Cx   = Qp;   // attention writes ctx in-place over Q (block-disjoint regions)
  bool useX = ws_size >= (size_t)56 * 1024 * 1024;

  dim3 blk(256);
  if (useX) {
    hipLaunchKernelGGL(convert_all, dim3(2048, 7), blk, 0, stream,
                       Wq, Wk, Wv, Wo, q, k, v, Wall, Xall);
    hipLaunchKernelGGL(qkv_gemm_bf16, dim3(8, 32, 3), blk, 0, stream,
                       Xall, Wall, bq, bk, bv, Qp, Kp, Vt);
  } else {
    hipLaunchKernelGGL(convert_all, dim3(512, 4), blk, 0, stream,
                       Wq, Wk, Wv, Wo, q, k, v, Wall, Wall);
    hipLaunchKernelGGL(qkv_gemm_f32, dim3(8, 32, 3), blk, 0, stream,
                       q, k, v, Wall, bq, bk, bv, Qp, Kp, Vt);
  }
  hipLaunchKernelGGL(attn, dim3(512), blk, 0, stream, Qp, Kp, Vt, Cx);
  hipLaunchKernelGGL(out_gemm, dim3(8, 64, 1), blk, 0, stream,
                     Cx, Wall + (3u << 20), bo, (float*)d_out);
}